// Round 1
// baseline (349.171 us; speedup 1.0000x reference)
//
#include <hip/hip_runtime.h>
#include <hip/hip_bf16.h>

#define T_  4096
#define H_  1024
#define E_  16
#define MI_ 512
#define SI_ 2048
#define TK_ 8192   // T_ * K(=2)

typedef __bf16 bf16;
typedef bf16  bf16x8 __attribute__((ext_vector_type(8)));
typedef bf16  bf16x4 __attribute__((ext_vector_type(4)));
typedef float f32x4  __attribute__((ext_vector_type(4)));

// ---------------- fp32 -> bf16 flat convert (vectorized) ----------------
__global__ void k_convert(const float* __restrict__ src, bf16* __restrict__ dst, int n4) {
    int i = blockIdx.x * blockDim.x + threadIdx.x;
    if (i < n4) {
        float4 v = reinterpret_cast<const float4*>(src)[i];
        bf16x4 o;
        o[0] = (bf16)v.x; o[1] = (bf16)v.y; o[2] = (bf16)v.z; o[3] = (bf16)v.w;
        reinterpret_cast<bf16x4*>(dst)[i] = o;
    }
}

// ---------------- fp32 [R][C] -> bf16 [C][R] transpose (per z-slice) ----------------
__global__ void k_transpose(const float* __restrict__ src, bf16* __restrict__ dst, int R, int C) {
    __shared__ float tile[32][33];
    size_t zoff = (size_t)blockIdx.z * (size_t)R * (size_t)C;
    src += zoff; dst += zoff;
    int c  = blockIdx.x * 32 + threadIdx.x;
    #pragma unroll
    for (int i = 0; i < 4; i++) {
        int r = blockIdx.y * 32 + threadIdx.y + i * 8;
        tile[threadIdx.y + i * 8][threadIdx.x] = src[(size_t)r * C + c];
    }
    __syncthreads();
    int rr = blockIdx.y * 32 + threadIdx.x;   // original row -> new col
    #pragma unroll
    for (int i = 0; i < 4; i++) {
        int cc = blockIdx.x * 32 + threadIdx.y + i * 8;  // original col -> new row
        dst[(size_t)cc * R + rr] = (bf16)tile[threadIdx.x][threadIdx.y + i * 8];
    }
}

// ---------------- router: logits (fp32), top-2, shared gate scalar ----------------
__global__ __launch_bounds__(256) void k_router(
    const float* __restrict__ x, const float* __restrict__ rw,
    const float* __restrict__ segw, float* __restrict__ logits_out,
    int* __restrict__ top_i, float* __restrict__ top_w,
    float* __restrict__ gate_scalar, int* __restrict__ counts)
{
    int wid = threadIdx.x >> 6, lane = threadIdx.x & 63;
    int t = blockIdx.x * 4 + wid;
    const float* xr = x + (size_t)t * H_;
    float acc[E_];
    #pragma unroll
    for (int e = 0; e < E_; e++) acc[e] = 0.f;
    float accg = 0.f;
    for (int j = 0; j < H_ / 64; j++) {
        int h = j * 64 + lane;
        float xv = xr[h];
        const float4* wrow = reinterpret_cast<const float4*>(rw + (size_t)h * E_);
        #pragma unroll
        for (int q = 0; q < 4; q++) {
            float4 w4 = wrow[q];
            acc[q*4+0] += xv * w4.x; acc[q*4+1] += xv * w4.y;
            acc[q*4+2] += xv * w4.z; acc[q*4+3] += xv * w4.w;
        }
        accg += xv * segw[h];
    }
    #pragma unroll
    for (int off = 32; off >= 1; off >>= 1) {
        #pragma unroll
        for (int e = 0; e < E_; e++) acc[e] += __shfl_xor(acc[e], off);
        accg += __shfl_xor(accg, off);
    }
    if (lane == 0) {
        float* lo = logits_out + (size_t)t * E_;
        #pragma unroll
        for (int e = 0; e < E_; e++) lo[e] = acc[e];
        int i0 = 0; float l0 = acc[0];
        #pragma unroll
        for (int e = 1; e < E_; e++) if (acc[e] > l0) { l0 = acc[e]; i0 = e; }
        int i1 = -1; float l1 = -1e30f;
        #pragma unroll
        for (int e = 0; e < E_; e++) if (e != i0 && acc[e] > l1) { l1 = acc[e]; i1 = e; }
        float w0 = 1.f / (1.f + expf(l1 - l0));   // p0/(p0+p1)
        top_i[t*2] = i0; top_i[t*2+1] = i1;
        top_w[t*2] = w0; top_w[t*2+1] = 1.f - w0;
        gate_scalar[t] = 1.f / (1.f + expf(-accg));
        atomicAdd(&counts[i0], 1); atomicAdd(&counts[i1], 1);
    }
}

// ---------------- prefix sum over 16 expert counts ----------------
__global__ void k_prefix(const int* __restrict__ counts, int* __restrict__ offsets, int* __restrict__ fill) {
    if (threadIdx.x == 0) {
        int s = 0;
        for (int e = 0; e < E_; e++) { offsets[e] = s; s += counts[e]; }
        offsets[E_] = s;
    }
    if (threadIdx.x < E_) fill[threadIdx.x] = 0;
}

// ---------------- scatter tokens into expert slots ----------------
__global__ void k_fill(const int* __restrict__ top_i, const int* __restrict__ offsets,
                       int* __restrict__ fill, int* __restrict__ slot_token, int* __restrict__ slot_pos)
{
    int t = blockIdx.x * blockDim.x + threadIdx.x;
    if (t < T_) {
        #pragma unroll
        for (int k = 0; k < 2; k++) {
            int e = top_i[t*2+k];
            int pos = offsets[e] + atomicAdd(&fill[e], 1);
            slot_token[pos] = t;
            slot_pos[t*2+k] = pos;
        }
    }
}

// ---------------- fused gate/up GEMM + silu-mul ----------------
// tile 128(M) x 64(N-of-MI, so 128 effective cols), BK=32, 4 waves, each wave 64x32 (x2 for g,u)
template<bool EXPERT>
__global__ __launch_bounds__(256) void k_gateup(
    const bf16* __restrict__ xb, const bf16* __restrict__ BgT, const bf16* __restrict__ BuT,
    const int* __restrict__ slot_token, const int* __restrict__ offsets,
    bf16* __restrict__ outH)
{
    constexpr int NOUT = EXPERT ? MI_ : SI_;
    int e = blockIdx.z;
    int base, cnt;
    if (EXPERT) { base = offsets[e]; cnt = offsets[e+1] - base; }
    else        { base = 0; cnt = T_; }
    int mt = blockIdx.y, nt = blockIdx.x;
    if (mt * 128 >= cnt) return;

    const bf16 *bg, *bu;
    if (EXPERT) {
        const bf16* wb = BgT + (size_t)e * 1024 * 1024;
        bg = wb + (size_t)(nt * 64) * 1024;
        bu = wb + (size_t)(512 + nt * 64) * 1024;
    } else {
        bg = BgT + (size_t)(nt * 64) * 1024;
        bu = BuT + (size_t)(nt * 64) * 1024;
    }

    __shared__ __align__(16) bf16 As[128 * 32];
    __shared__ __align__(16) bf16 Bgs[64 * 32];
    __shared__ __align__(16) bf16 Bus[64 * 32];

    int tid = threadIdx.x;
    int ar = tid >> 2;            // 0..63
    int ac = (tid & 3) * 8;       // k-chunk within 32
    const bf16 *arow0, *arow1;
    {
        int r0 = mt * 128 + ar, r1 = r0 + 64;
        if (EXPERT) {
            int s0 = base + (r0 < cnt ? r0 : cnt - 1);
            int s1 = base + (r1 < cnt ? r1 : cnt - 1);
            arow0 = xb + (size_t)slot_token[s0] * H_;
            arow1 = xb + (size_t)slot_token[s1] * H_;
        } else {
            arow0 = xb + (size_t)r0 * H_;
            arow1 = xb + (size_t)r1 * H_;
        }
    }
    int wid = tid >> 6, lane = tid & 63;
    int wm = wid >> 1, wn = wid & 1;
    int lr = lane & 15, kq = lane >> 4;

    f32x4 accg[4][2], accu[4][2];
    #pragma unroll
    for (int i = 0; i < 4; i++)
        #pragma unroll
        for (int j = 0; j < 2; j++) {
            accg[i][j] = (f32x4){0.f,0.f,0.f,0.f};
            accu[i][j] = (f32x4){0.f,0.f,0.f,0.f};
        }

    for (int k0 = 0; k0 < H_; k0 += 32) {
        bf16x8 a0  = *reinterpret_cast<const bf16x8*>(arow0 + k0 + ac);
        bf16x8 a1  = *reinterpret_cast<const bf16x8*>(arow1 + k0 + ac);
        bf16x8 bgv = *reinterpret_cast<const bf16x8*>(bg + (size_t)ar * 1024 + k0 + ac);
        bf16x8 buv = *reinterpret_cast<const bf16x8*>(bu + (size_t)ar * 1024 + k0 + ac);
        __syncthreads();
        *reinterpret_cast<bf16x8*>(&As[ar * 32 + ac])        = a0;
        *reinterpret_cast<bf16x8*>(&As[(ar + 64) * 32 + ac]) = a1;
        *reinterpret_cast<bf16x8*>(&Bgs[ar * 32 + ac])       = bgv;
        *reinterpret_cast<bf16x8*>(&Bus[ar * 32 + ac])       = buv;
        __syncthreads();
        bf16x8 af[4], bgf[2], buf_[2];
        #pragma unroll
        for (int mi = 0; mi < 4; mi++)
            af[mi] = *reinterpret_cast<const bf16x8*>(&As[(wm*64 + mi*16 + lr) * 32 + kq * 8]);
        #pragma unroll
        for (int ni = 0; ni < 2; ni++) {
            bgf[ni]  = *reinterpret_cast<const bf16x8*>(&Bgs[(wn*32 + ni*16 + lr) * 32 + kq * 8]);
            buf_[ni] = *reinterpret_cast<const bf16x8*>(&Bus[(wn*32 + ni*16 + lr) * 32 + kq * 8]);
        }
        #pragma unroll
        for (int mi = 0; mi < 4; mi++)
            #pragma unroll
            for (int ni = 0; ni < 2; ni++) {
                accg[mi][ni] = __builtin_amdgcn_mfma_f32_16x16x32_bf16(af[mi], bgf[ni], accg[mi][ni], 0, 0, 0);
                accu[mi][ni] = __builtin_amdgcn_mfma_f32_16x16x32_bf16(af[mi], buf_[ni], accu[mi][ni], 0, 0, 0);
            }
    }
    #pragma unroll
    for (int mi = 0; mi < 4; mi++)
        #pragma unroll
        for (int ni = 0; ni < 2; ni++)
            #pragma unroll
            for (int r = 0; r < 4; r++) {
                int row = mt * 128 + wm * 64 + mi * 16 + kq * 4 + r;
                if (row < cnt) {
                    int col = nt * 64 + wn * 32 + ni * 16 + lr;
                    float g = accg[mi][ni][r], u = accu[mi][ni][r];
                    float hv = u * (g / (1.f + expf(-g)));
                    outH[(size_t)(base + row) * NOUT + col] = (bf16)hv;
                }
            }
}

// ---------------- down GEMM (expert: ->bf16 eo; shared: ->f32 d_out w/ sigmoid gate) ----------------
template<bool EXPERT>
__global__ __launch_bounds__(256) void k_down(
    const bf16* __restrict__ Ah, const bf16* __restrict__ BT,
    const int* __restrict__ offsets, const float* __restrict__ gate_scalar,
    bf16* __restrict__ eo, float* __restrict__ out_f32)
{
    constexpr int KD = EXPERT ? MI_ : SI_;
    int e = blockIdx.z;
    int base, cnt;
    if (EXPERT) { base = offsets[e]; cnt = offsets[e+1] - base; }
    else        { base = 0; cnt = T_; }
    int mt = blockIdx.y, nt = blockIdx.x;
    if (mt * 128 >= cnt) return;

    const bf16* bp = EXPERT ? BT + (size_t)e * H_ * MI_ + (size_t)(nt * 64) * KD
                            : BT + (size_t)(nt * 64) * KD;

    __shared__ __align__(16) bf16 As[128 * 32];
    __shared__ __align__(16) bf16 Bs[64 * 32];

    int tid = threadIdx.x;
    int ar = tid >> 2, ac = (tid & 3) * 8;
    int r0 = mt * 128 + ar, r1 = r0 + 64;
    int cr0 = r0 < cnt ? r0 : cnt - 1;
    int cr1 = r1 < cnt ? r1 : cnt - 1;
    const bf16* arow0 = Ah + (size_t)(base + cr0) * KD;
    const bf16* arow1 = Ah + (size_t)(base + cr1) * KD;

    int wid = tid >> 6, lane = tid & 63;
    int wm = wid >> 1, wn = wid & 1;
    int lr = lane & 15, kq = lane >> 4;

    f32x4 acc[4][2];
    #pragma unroll
    for (int i = 0; i < 4; i++)
        #pragma unroll
        for (int j = 0; j < 2; j++) acc[i][j] = (f32x4){0.f,0.f,0.f,0.f};

    for (int k0 = 0; k0 < KD; k0 += 32) {
        bf16x8 a0 = *reinterpret_cast<const bf16x8*>(arow0 + k0 + ac);
        bf16x8 a1 = *reinterpret_cast<const bf16x8*>(arow1 + k0 + ac);
        bf16x8 bv = *reinterpret_cast<const bf16x8*>(bp + (size_t)ar * KD + k0 + ac);
        __syncthreads();
        *reinterpret_cast<bf16x8*>(&As[ar * 32 + ac])        = a0;
        *reinterpret_cast<bf16x8*>(&As[(ar + 64) * 32 + ac]) = a1;
        *reinterpret_cast<bf16x8*>(&Bs[ar * 32 + ac])        = bv;
        __syncthreads();
        bf16x8 af[4], bf_[2];
        #pragma unroll
        for (int mi = 0; mi < 4; mi++)
            af[mi] = *reinterpret_cast<const bf16x8*>(&As[(wm*64 + mi*16 + lr) * 32 + kq * 8]);
        #pragma unroll
        for (int ni = 0; ni < 2; ni++)
            bf_[ni] = *reinterpret_cast<const bf16x8*>(&Bs[(wn*32 + ni*16 + lr) * 32 + kq * 8]);
        #pragma unroll
        for (int mi = 0; mi < 4; mi++)
            #pragma unroll
            for (int ni = 0; ni < 2; ni++)
                acc[mi][ni] = __builtin_amdgcn_mfma_f32_16x16x32_bf16(af[mi], bf_[ni], acc[mi][ni], 0, 0, 0);
    }
    #pragma unroll
    for (int mi = 0; mi < 4; mi++)
        #pragma unroll
        for (int ni = 0; ni < 2; ni++)
            #pragma unroll
            for (int r = 0; r < 4; r++) {
                int row = mt * 128 + wm * 64 + mi * 16 + kq * 4 + r;
                if (row < cnt) {
                    int col = nt * 64 + wn * 32 + ni * 16 + lr;
                    float v = acc[mi][ni][r];
                    if (EXPERT) eo[(size_t)(base + row) * H_ + col] = (bf16)v;
                    else        out_f32[(size_t)row * H_ + col] = gate_scalar[row] * v;
                }
            }
}

// ---------------- combine: out += w0*eo[s0] + w1*eo[s1] ----------------
__global__ void k_combine(float* __restrict__ out, const bf16* __restrict__ eo,
                          const int* __restrict__ slot_pos, const float* __restrict__ top_w)
{
    int i = blockIdx.x * blockDim.x + threadIdx.x;   // T_*256 threads
    int t = i >> 8;
    int q = (i & 255) * 4;
    int s0 = slot_pos[t*2], s1 = slot_pos[t*2+1];
    float w0 = top_w[t*2], w1 = top_w[t*2+1];
    bf16x4 e0 = *reinterpret_cast<const bf16x4*>(eo + (size_t)s0 * H_ + q);
    bf16x4 e1 = *reinterpret_cast<const bf16x4*>(eo + (size_t)s1 * H_ + q);
    float4* op = reinterpret_cast<float4*>(out) + i;
    float4 so = *op;
    float4 r;
    r.x = so.x + w0 * (float)e0[0] + w1 * (float)e1[0];
    r.y = so.y + w0 * (float)e0[1] + w1 * (float)e1[1];
    r.z = so.z + w0 * (float)e0[2] + w1 * (float)e1[2];
    r.w = so.w + w0 * (float)e0[3] + w1 * (float)e1[3];
    *op = r;
}

extern "C" void kernel_launch(void* const* d_in, const int* in_sizes, int n_in,
                              void* d_out, int out_size, void* d_ws, size_t ws_size,
                              hipStream_t stream) {
    const float* x    = (const float*)d_in[0];
    const float* rw   = (const float*)d_in[1];
    const float* wgu  = (const float*)d_in[2];
    const float* wdn  = (const float*)d_in[3];
    const float* wsg  = (const float*)d_in[4];
    const float* wsu  = (const float*)d_in[5];
    const float* wsd  = (const float*)d_in[6];
    const float* segw = (const float*)d_in[7];
    float* out    = (float*)d_out;
    float* logits = (float*)d_out + (size_t)T_ * H_;

    char* p = (char*)d_ws;
    bf16* xb      = (bf16*)p;  p += (size_t)T_ * H_ * 2;
    bf16* w_guT   = (bf16*)p;  p += (size_t)E_ * H_ * (2*MI_) * 2;
    bf16* w_dnT   = (bf16*)p;  p += (size_t)E_ * MI_ * H_ * 2;
    bf16* w_sgT   = (bf16*)p;  p += (size_t)H_ * SI_ * 2;
    bf16* w_suT   = (bf16*)p;  p += (size_t)H_ * SI_ * 2;
    bf16* w_sdT   = (bf16*)p;  p += (size_t)SI_ * H_ * 2;
    bf16* hiddenE = (bf16*)p;  p += (size_t)TK_ * MI_ * 2;
    bf16* sh_hid  = (bf16*)p;  p += (size_t)T_ * SI_ * 2;
    bf16* eo      = (bf16*)p;  p += (size_t)TK_ * H_ * 2;
    float* gate_s = (float*)p; p += (size_t)T_ * 4;
    int*  top_i   = (int*)p;   p += (size_t)T_ * 2 * 4;
    float* top_w  = (float*)p; p += (size_t)T_ * 2 * 4;
    int*  slot_pos= (int*)p;   p += (size_t)T_ * 2 * 4;
    int*  slot_tok= (int*)p;   p += (size_t)TK_ * 4;
    int*  counts  = (int*)p;   p += 16 * 4;
    int*  fill    = (int*)p;   p += 16 * 4;
    int*  offsets = (int*)p;   p += 17 * 4;

    // conversions + transposes
    k_convert<<<dim3(T_*H_/4/256), 256, 0, stream>>>(x, xb, T_*H_/4);
    k_transpose<<<dim3(32, 32, 16), dim3(32, 8), 0, stream>>>(wgu, w_guT, 1024, 1024);
    k_transpose<<<dim3(32, 16, 16), dim3(32, 8), 0, stream>>>(wdn, w_dnT, 512, 1024);
    k_transpose<<<dim3(64, 32, 1),  dim3(32, 8), 0, stream>>>(wsg, w_sgT, 1024, 2048);
    k_transpose<<<dim3(64, 32, 1),  dim3(32, 8), 0, stream>>>(wsu, w_suT, 1024, 2048);
    k_transpose<<<dim3(32, 64, 1),  dim3(32, 8), 0, stream>>>(wsd, w_sdT, 2048, 1024);

    hipMemsetAsync(counts, 0, 32 * 4, stream);  // counts + fill

    k_router<<<dim3(T_/4), 256, 0, stream>>>(x, rw, segw, logits, top_i, top_w, gate_s, counts);
    k_prefix<<<dim3(1), 64, 0, stream>>>(counts, offsets, fill);
    k_fill<<<dim3(T_/256), 256, 0, stream>>>(top_i, offsets, fill, slot_tok, slot_pos);

    // expert path
    k_gateup<true><<<dim3(MI_/64, 32, E_), 256, 0, stream>>>(xb, w_guT, w_guT, slot_tok, offsets, hiddenE);
    k_down<true><<<dim3(H_/64, 32, E_), 256, 0, stream>>>(hiddenE, w_dnT, offsets, gate_s, eo, out);

    // shared expert path (writes d_out directly with sigmoid gate scale)
    k_gateup<false><<<dim3(SI_/64, 32, 1), 256, 0, stream>>>(xb, w_sgT, w_suT, slot_tok, offsets, sh_hid);
    k_down<false><<<dim3(H_/64, 32, 1), 256, 0, stream>>>(sh_hid, w_sdT, offsets, gate_s, eo, out);

    // combine expert contributions into d_out
    k_combine<<<dim3(T_*256/256), 256, 0, stream>>>(out, eo, slot_pos, top_w);
}

// Round 2
// 246.319 us; speedup vs baseline: 1.4176x; 1.4176x over previous
//
#include <hip/hip_runtime.h>
#include <hip/hip_bf16.h>

#define T_  4096
#define H_  1024
#define E_  16
#define MI_ 512
#define SI_ 2048
#define TK_ 8192   // T_ * K(=2)

typedef __bf16 bf16;
typedef bf16  bf16x8 __attribute__((ext_vector_type(8)));
typedef bf16  bf16x4 __attribute__((ext_vector_type(4)));
typedef float f32x4  __attribute__((ext_vector_type(4)));

// ---------------- fp32 -> bf16 flat convert (vectorized) ----------------
__global__ void k_convert(const float* __restrict__ src, bf16* __restrict__ dst, int n4) {
    int i = blockIdx.x * blockDim.x + threadIdx.x;
    if (i < n4) {
        float4 v = reinterpret_cast<const float4*>(src)[i];
        bf16x4 o;
        o[0] = (bf16)v.x; o[1] = (bf16)v.y; o[2] = (bf16)v.z; o[3] = (bf16)v.w;
        reinterpret_cast<bf16x4*>(dst)[i] = o;
    }
}

// ---------------- fp32 [R][C] -> bf16 [C][R] transpose (per z-slice) ----------------
__global__ void k_transpose(const float* __restrict__ src, bf16* __restrict__ dst, int R, int C) {
    __shared__ float tile[32][33];
    size_t zoff = (size_t)blockIdx.z * (size_t)R * (size_t)C;
    src += zoff; dst += zoff;
    int c  = blockIdx.x * 32 + threadIdx.x;
    #pragma unroll
    for (int i = 0; i < 4; i++) {
        int r = blockIdx.y * 32 + threadIdx.y + i * 8;
        tile[threadIdx.y + i * 8][threadIdx.x] = src[(size_t)r * C + c];
    }
    __syncthreads();
    int rr = blockIdx.y * 32 + threadIdx.x;   // original row -> new col
    #pragma unroll
    for (int i = 0; i < 4; i++) {
        int cc = blockIdx.x * 32 + threadIdx.y + i * 8;  // original col -> new row
        dst[(size_t)cc * R + rr] = (bf16)tile[threadIdx.x][threadIdx.y + i * 8];
    }
}

// ---------------- router: logits (fp32), top-2, shared gate scalar. NO atomics. ----------------
__global__ __launch_bounds__(256) void k_router(
    const float* __restrict__ x, const float* __restrict__ rw,
    const float* __restrict__ segw, float* __restrict__ logits_out,
    int* __restrict__ top_i, float* __restrict__ top_w,
    float* __restrict__ gate_scalar)
{
    int wid = threadIdx.x >> 6, lane = threadIdx.x & 63;
    int t = blockIdx.x * 4 + wid;
    const float* xr = x + (size_t)t * H_;
    float acc[E_];
    #pragma unroll
    for (int e = 0; e < E_; e++) acc[e] = 0.f;
    float accg = 0.f;
    for (int j = 0; j < H_ / 64; j++) {
        int h = j * 64 + lane;
        float xv = xr[h];
        const float4* wrow = reinterpret_cast<const float4*>(rw + (size_t)h * E_);
        #pragma unroll
        for (int q = 0; q < 4; q++) {
            float4 w4 = wrow[q];
            acc[q*4+0] += xv * w4.x; acc[q*4+1] += xv * w4.y;
            acc[q*4+2] += xv * w4.z; acc[q*4+3] += xv * w4.w;
        }
        accg += xv * segw[h];
    }
    #pragma unroll
    for (int off = 32; off >= 1; off >>= 1) {
        #pragma unroll
        for (int e = 0; e < E_; e++) acc[e] += __shfl_xor(acc[e], off);
        accg += __shfl_xor(accg, off);
    }
    if (lane == 0) {
        float* lo = logits_out + (size_t)t * E_;
        #pragma unroll
        for (int e = 0; e < E_; e++) lo[e] = acc[e];
        int i0 = 0; float l0 = acc[0];
        #pragma unroll
        for (int e = 1; e < E_; e++) if (acc[e] > l0) { l0 = acc[e]; i0 = e; }
        int i1 = -1; float l1 = -1e30f;
        #pragma unroll
        for (int e = 0; e < E_; e++) if (e != i0 && acc[e] > l1) { l1 = acc[e]; i1 = e; }
        float w0 = 1.f / (1.f + expf(l1 - l0));   // p0/(p0+p1)
        top_i[t*2] = i0; top_i[t*2+1] = i1;
        top_w[t*2] = w0; top_w[t*2+1] = 1.f - w0;
        gate_scalar[t] = 1.f / (1.f + expf(-accg));
    }
}

// ---------------- counts + offsets from top_i, single block, no global atomics ----------------
__global__ __launch_bounds__(256) void k_count(const int* __restrict__ top_i, int* __restrict__ offsets) {
    __shared__ int hist[256][17];   // stride 17: bank-conflict-free
    int tid = threadIdx.x;
    #pragma unroll
    for (int e = 0; e < E_; e++) hist[tid][e] = 0;
    __syncthreads();
    const int* mine = top_i + tid * 32;
    #pragma unroll
    for (int j = 0; j < 32; j++) hist[tid][mine[j]]++;
    __syncthreads();
    if (tid < E_) {
        int s = 0;
        for (int r = 0; r < 256; r++) s += hist[r][tid];
        hist[0][tid] = s;   // reuse as count staging
    }
    __syncthreads();
    if (tid == 0) {
        int s = 0;
        for (int e = 0; e < E_; e++) { offsets[e] = s; s += hist[0][e]; }
        offsets[E_] = s;
    }
}

// ---------------- deterministic slot assignment by rank (prefix scan), one block per expert ----------------
__global__ __launch_bounds__(256) void k_fillscan(
    const int* __restrict__ top_i, const int* __restrict__ offsets,
    int* __restrict__ slot_token, int* __restrict__ slot_pos)
{
    int e = blockIdx.x;
    int tid = threadIdx.x;
    int lane = tid & 63, w = tid >> 6;
    __shared__ int wsum[4];

    int t0 = tid * 16;
    unsigned f0 = 0, f1 = 0;   // bit j: token t0+j picked e as top0 / top1
    int c = 0;
    #pragma unroll
    for (int j = 0; j < 16; j++) {
        int t = t0 + j;
        int a = top_i[t*2], b = top_i[t*2+1];
        if (a == e)      { f0 |= 1u << j; c++; }
        else if (b == e) { f1 |= 1u << j; c++; }
    }
    // inclusive wave scan of c
    int incl = c;
    #pragma unroll
    for (int off = 1; off < 64; off <<= 1) {
        int v = __shfl_up(incl, off);
        if (lane >= off) incl += v;
    }
    if (lane == 63) wsum[w] = incl;
    __syncthreads();
    int wbase = 0;
    for (int i = 0; i < w; i++) wbase += wsum[i];
    int pos = offsets[e] + wbase + (incl - c);
    #pragma unroll
    for (int j = 0; j < 16; j++) {
        int t = t0 + j;
        if ((f0 >> j) & 1u)      { slot_token[pos] = t; slot_pos[t*2]   = pos; pos++; }
        else if ((f1 >> j) & 1u) { slot_token[pos] = t; slot_pos[t*2+1] = pos; pos++; }
    }
}

// ---------------- fused gate/up GEMM + silu-mul ----------------
template<bool EXPERT>
__global__ __launch_bounds__(256) void k_gateup(
    const bf16* __restrict__ xb, const bf16* __restrict__ BgT, const bf16* __restrict__ BuT,
    const int* __restrict__ slot_token, const int* __restrict__ offsets,
    bf16* __restrict__ outH)
{
    constexpr int NOUT = EXPERT ? MI_ : SI_;
    int e = blockIdx.z;
    int base, cnt;
    if (EXPERT) { base = offsets[e]; cnt = offsets[e+1] - base; }
    else        { base = 0; cnt = T_; }
    int mt = blockIdx.y, nt = blockIdx.x;
    if (mt * 128 >= cnt) return;

    const bf16 *bg, *bu;
    if (EXPERT) {
        const bf16* wb = BgT + (size_t)e * 1024 * 1024;
        bg = wb + (size_t)(nt * 64) * 1024;
        bu = wb + (size_t)(512 + nt * 64) * 1024;
    } else {
        bg = BgT + (size_t)(nt * 64) * 1024;
        bu = BuT + (size_t)(nt * 64) * 1024;
    }

    __shared__ __align__(16) bf16 As[128 * 32];
    __shared__ __align__(16) bf16 Bgs[64 * 32];
    __shared__ __align__(16) bf16 Bus[64 * 32];

    int tid = threadIdx.x;
    int ar = tid >> 2;            // 0..63
    int ac = (tid & 3) * 8;       // k-chunk within 32
    const bf16 *arow0, *arow1;
    {
        int r0 = mt * 128 + ar, r1 = r0 + 64;
        if (EXPERT) {
            int s0 = base + (r0 < cnt ? r0 : cnt - 1);
            int s1 = base + (r1 < cnt ? r1 : cnt - 1);
            arow0 = xb + (size_t)slot_token[s0] * H_;
            arow1 = xb + (size_t)slot_token[s1] * H_;
        } else {
            arow0 = xb + (size_t)r0 * H_;
            arow1 = xb + (size_t)r1 * H_;
        }
    }
    int wid = tid >> 6, lane = tid & 63;
    int wm = wid >> 1, wn = wid & 1;
    int lr = lane & 15, kq = lane >> 4;

    f32x4 accg[4][2], accu[4][2];
    #pragma unroll
    for (int i = 0; i < 4; i++)
        #pragma unroll
        for (int j = 0; j < 2; j++) {
            accg[i][j] = (f32x4){0.f,0.f,0.f,0.f};
            accu[i][j] = (f32x4){0.f,0.f,0.f,0.f};
        }

    for (int k0 = 0; k0 < H_; k0 += 32) {
        bf16x8 a0  = *reinterpret_cast<const bf16x8*>(arow0 + k0 + ac);
        bf16x8 a1  = *reinterpret_cast<const bf16x8*>(arow1 + k0 + ac);
        bf16x8 bgv = *reinterpret_cast<const bf16x8*>(bg + (size_t)ar * 1024 + k0 + ac);
        bf16x8 buv = *reinterpret_cast<const bf16x8*>(bu + (size_t)ar * 1024 + k0 + ac);
        __syncthreads();
        *reinterpret_cast<bf16x8*>(&As[ar * 32 + ac])        = a0;
        *reinterpret_cast<bf16x8*>(&As[(ar + 64) * 32 + ac]) = a1;
        *reinterpret_cast<bf16x8*>(&Bgs[ar * 32 + ac])       = bgv;
        *reinterpret_cast<bf16x8*>(&Bus[ar * 32 + ac])       = buv;
        __syncthreads();
        bf16x8 af[4], bgf[2], buf_[2];
        #pragma unroll
        for (int mi = 0; mi < 4; mi++)
            af[mi] = *reinterpret_cast<const bf16x8*>(&As[(wm*64 + mi*16 + lr) * 32 + kq * 8]);
        #pragma unroll
        for (int ni = 0; ni < 2; ni++) {
            bgf[ni]  = *reinterpret_cast<const bf16x8*>(&Bgs[(wn*32 + ni*16 + lr) * 32 + kq * 8]);
            buf_[ni] = *reinterpret_cast<const bf16x8*>(&Bus[(wn*32 + ni*16 + lr) * 32 + kq * 8]);
        }
        #pragma unroll
        for (int mi = 0; mi < 4; mi++)
            #pragma unroll
            for (int ni = 0; ni < 2; ni++) {
                accg[mi][ni] = __builtin_amdgcn_mfma_f32_16x16x32_bf16(af[mi], bgf[ni], accg[mi][ni], 0, 0, 0);
                accu[mi][ni] = __builtin_amdgcn_mfma_f32_16x16x32_bf16(af[mi], buf_[ni], accu[mi][ni], 0, 0, 0);
            }
    }
    #pragma unroll
    for (int mi = 0; mi < 4; mi++)
        #pragma unroll
        for (int ni = 0; ni < 2; ni++)
            #pragma unroll
            for (int r = 0; r < 4; r++) {
                int row = mt * 128 + wm * 64 + mi * 16 + kq * 4 + r;
                if (row < cnt) {
                    int col = nt * 64 + wn * 32 + ni * 16 + lr;
                    float g = accg[mi][ni][r], u = accu[mi][ni][r];
                    float hv = u * (g / (1.f + expf(-g)));
                    outH[(size_t)(base + row) * NOUT + col] = (bf16)hv;
                }
            }
}

// ---------------- down GEMM (expert: ->bf16 eo; shared: ->f32 d_out w/ sigmoid gate) ----------------
template<bool EXPERT>
__global__ __launch_bounds__(256) void k_down(
    const bf16* __restrict__ Ah, const bf16* __restrict__ BT,
    const int* __restrict__ offsets, const float* __restrict__ gate_scalar,
    bf16* __restrict__ eo, float* __restrict__ out_f32)
{
    constexpr int KD = EXPERT ? MI_ : SI_;
    int e = blockIdx.z;
    int base, cnt;
    if (EXPERT) { base = offsets[e]; cnt = offsets[e+1] - base; }
    else        { base = 0; cnt = T_; }
    int mt = blockIdx.y, nt = blockIdx.x;
    if (mt * 128 >= cnt) return;

    const bf16* bp = EXPERT ? BT + (size_t)e * H_ * MI_ + (size_t)(nt * 64) * KD
                            : BT + (size_t)(nt * 64) * KD;

    __shared__ __align__(16) bf16 As[128 * 32];
    __shared__ __align__(16) bf16 Bs[64 * 32];

    int tid = threadIdx.x;
    int ar = tid >> 2, ac = (tid & 3) * 8;
    int r0 = mt * 128 + ar, r1 = r0 + 64;
    int cr0 = r0 < cnt ? r0 : cnt - 1;
    int cr1 = r1 < cnt ? r1 : cnt - 1;
    const bf16* arow0 = Ah + (size_t)(base + cr0) * KD;
    const bf16* arow1 = Ah + (size_t)(base + cr1) * KD;

    int wid = tid >> 6, lane = tid & 63;
    int wm = wid >> 1, wn = wid & 1;
    int lr = lane & 15, kq = lane >> 4;

    f32x4 acc[4][2];
    #pragma unroll
    for (int i = 0; i < 4; i++)
        #pragma unroll
        for (int j = 0; j < 2; j++) acc[i][j] = (f32x4){0.f,0.f,0.f,0.f};

    for (int k0 = 0; k0 < KD; k0 += 32) {
        bf16x8 a0 = *reinterpret_cast<const bf16x8*>(arow0 + k0 + ac);
        bf16x8 a1 = *reinterpret_cast<const bf16x8*>(arow1 + k0 + ac);
        bf16x8 bv = *reinterpret_cast<const bf16x8*>(bp + (size_t)ar * KD + k0 + ac);
        __syncthreads();
        *reinterpret_cast<bf16x8*>(&As[ar * 32 + ac])        = a0;
        *reinterpret_cast<bf16x8*>(&As[(ar + 64) * 32 + ac]) = a1;
        *reinterpret_cast<bf16x8*>(&Bs[ar * 32 + ac])        = bv;
        __syncthreads();
        bf16x8 af[4], bf_[2];
        #pragma unroll
        for (int mi = 0; mi < 4; mi++)
            af[mi] = *reinterpret_cast<const bf16x8*>(&As[(wm*64 + mi*16 + lr) * 32 + kq * 8]);
        #pragma unroll
        for (int ni = 0; ni < 2; ni++)
            bf_[ni] = *reinterpret_cast<const bf16x8*>(&Bs[(wn*32 + ni*16 + lr) * 32 + kq * 8]);
        #pragma unroll
        for (int mi = 0; mi < 4; mi++)
            #pragma unroll
            for (int ni = 0; ni < 2; ni++)
                acc[mi][ni] = __builtin_amdgcn_mfma_f32_16x16x32_bf16(af[mi], bf_[ni], acc[mi][ni], 0, 0, 0);
    }
    #pragma unroll
    for (int mi = 0; mi < 4; mi++)
        #pragma unroll
        for (int ni = 0; ni < 2; ni++)
            #pragma unroll
            for (int r = 0; r < 4; r++) {
                int row = mt * 128 + wm * 64 + mi * 16 + kq * 4 + r;
                if (row < cnt) {
                    int col = nt * 64 + wn * 32 + ni * 16 + lr;
                    float v = acc[mi][ni][r];
                    if (EXPERT) eo[(size_t)(base + row) * H_ + col] = (bf16)v;
                    else        out_f32[(size_t)row * H_ + col] = gate_scalar[row] * v;
                }
            }
}

// ---------------- combine: out += w0*eo[s0] + w1*eo[s1] ----------------
__global__ void k_combine(float* __restrict__ out, const bf16* __restrict__ eo,
                          const int* __restrict__ slot_pos, const float* __restrict__ top_w)
{
    int i = blockIdx.x * blockDim.x + threadIdx.x;   // T_*256 threads
    int t = i >> 8;
    int q = (i & 255) * 4;
    int s0 = slot_pos[t*2], s1 = slot_pos[t*2+1];
    float w0 = top_w[t*2], w1 = top_w[t*2+1];
    bf16x4 e0 = *reinterpret_cast<const bf16x4*>(eo + (size_t)s0 * H_ + q);
    bf16x4 e1 = *reinterpret_cast<const bf16x4*>(eo + (size_t)s1 * H_ + q);
    float4* op = reinterpret_cast<float4*>(out) + i;
    float4 so = *op;
    float4 r;
    r.x = so.x + w0 * (float)e0[0] + w1 * (float)e1[0];
    r.y = so.y + w0 * (float)e0[1] + w1 * (float)e1[1];
    r.z = so.z + w0 * (float)e0[2] + w1 * (float)e1[2];
    r.w = so.w + w0 * (float)e0[3] + w1 * (float)e1[3];
    *op = r;
}

extern "C" void kernel_launch(void* const* d_in, const int* in_sizes, int n_in,
                              void* d_out, int out_size, void* d_ws, size_t ws_size,
                              hipStream_t stream) {
    const float* x    = (const float*)d_in[0];
    const float* rw   = (const float*)d_in[1];
    const float* wgu  = (const float*)d_in[2];
    const float* wdn  = (const float*)d_in[3];
    const float* wsg  = (const float*)d_in[4];
    const float* wsu  = (const float*)d_in[5];
    const float* wsd  = (const float*)d_in[6];
    const float* segw = (const float*)d_in[7];
    float* out    = (float*)d_out;
    float* logits = (float*)d_out + (size_t)T_ * H_;

    char* p = (char*)d_ws;
    bf16* xb      = (bf16*)p;  p += (size_t)T_ * H_ * 2;
    bf16* w_guT   = (bf16*)p;  p += (size_t)E_ * H_ * (2*MI_) * 2;
    bf16* w_dnT   = (bf16*)p;  p += (size_t)E_ * MI_ * H_ * 2;
    bf16* w_sgT   = (bf16*)p;  p += (size_t)H_ * SI_ * 2;
    bf16* w_suT   = (bf16*)p;  p += (size_t)H_ * SI_ * 2;
    bf16* w_sdT   = (bf16*)p;  p += (size_t)SI_ * H_ * 2;
    bf16* hiddenE = (bf16*)p;  p += (size_t)TK_ * MI_ * 2;
    bf16* sh_hid  = (bf16*)p;  p += (size_t)T_ * SI_ * 2;
    bf16* eo      = (bf16*)p;  p += (size_t)TK_ * H_ * 2;
    float* gate_s = (float*)p; p += (size_t)T_ * 4;
    int*  top_i   = (int*)p;   p += (size_t)T_ * 2 * 4;
    float* top_w  = (float*)p; p += (size_t)T_ * 2 * 4;
    int*  slot_pos= (int*)p;   p += (size_t)T_ * 2 * 4;
    int*  slot_tok= (int*)p;   p += (size_t)TK_ * 4;
    int*  offsets = (int*)p;   p += 17 * 4;

    // conversions + transposes
    k_convert<<<dim3(T_*H_/4/256), 256, 0, stream>>>(x, xb, T_*H_/4);
    k_transpose<<<dim3(32, 32, 16), dim3(32, 8), 0, stream>>>(wgu, w_guT, 1024, 1024);
    k_transpose<<<dim3(32, 16, 16), dim3(32, 8), 0, stream>>>(wdn, w_dnT, 512, 1024);
    k_transpose<<<dim3(64, 32, 1),  dim3(32, 8), 0, stream>>>(wsg, w_sgT, 1024, 2048);
    k_transpose<<<dim3(64, 32, 1),  dim3(32, 8), 0, stream>>>(wsu, w_suT, 1024, 2048);
    k_transpose<<<dim3(32, 64, 1),  dim3(32, 8), 0, stream>>>(wsd, w_sdT, 2048, 1024);

    // routing (atomic-free)
    k_router<<<dim3(T_/4), 256, 0, stream>>>(x, rw, segw, logits, top_i, top_w, gate_s);
    k_count<<<dim3(1), 256, 0, stream>>>(top_i, offsets);
    k_fillscan<<<dim3(E_), 256, 0, stream>>>(top_i, offsets, slot_tok, slot_pos);

    // expert path
    k_gateup<true><<<dim3(MI_/64, 32, E_), 256, 0, stream>>>(xb, w_guT, w_guT, slot_tok, offsets, hiddenE);
    k_down<true><<<dim3(H_/64, 32, E_), 256, 0, stream>>>(hiddenE, w_dnT, offsets, gate_s, eo, out);

    // shared expert path (writes d_out directly with sigmoid gate scale)
    k_gateup<false><<<dim3(SI_/64, 32, 1), 256, 0, stream>>>(xb, w_sgT, w_suT, slot_tok, offsets, sh_hid);
    k_down<false><<<dim3(H_/64, 32, 1), 256, 0, stream>>>(sh_hid, w_sdT, offsets, gate_s, eo, out);

    // combine expert contributions into d_out
    k_combine<<<dim3(T_*256/256), 256, 0, stream>>>(out, eo, slot_pos, top_w);
}